// Round 15
// baseline (156.567 us; speedup 1.0000x reference)
//
#include <hip/hip_runtime.h>

#define BATCH 4096
#define DICT  16384
#define KDIM  512
#define CAT   128
#define ND    16              // split-K over dict
#define DSLICE (DICT/ND)      // 1024
#define DCH   128             // d-chunk per dc iteration
#define BT    128             // b rows per block -> grid 512, 2 blocks/CU

typedef __attribute__((ext_vector_type(4))) float          f32x4;
typedef __attribute__((ext_vector_type(8))) short          short8;
typedef __attribute__((ext_vector_type(8))) unsigned short ushort8;
typedef __attribute__((ext_vector_type(4))) int            intx4;

__device__ __forceinline__ unsigned short f2bf(float f) {
  unsigned int u = __float_as_uint(f);
  return (unsigned short)((u + 0x7fffu + ((u >> 16) & 1u)) >> 16);  // RNE
}

__device__ __forceinline__ unsigned int cvtpk_bf16(float lo, float hi) {
  unsigned int r;
  asm volatile("v_cvt_pk_bf16_f32 %0, %1, %2" : "=v"(r) : "v"(lo), "v"(hi));
  return r;
}

#define AS1 __attribute__((address_space(1)))
#define AS3 __attribute__((address_space(3)))
__device__ __forceinline__ void gl_lds16(const void* g, void* l) {
  // 16B/lane; LDS dest = wave-uniform base + lane*16 (linear). Swizzle is
  // pre-applied on the GLOBAL source address (m173 pattern).
  __builtin_amdgcn_global_load_lds((AS1 void*)(g), (AS3 void*)(l), 16, 0, 0);
}

template <int N>
__device__ __forceinline__ void waitv() {
  if constexpr (N == 0)      asm volatile("s_waitcnt vmcnt(0)" ::: "memory");
  else if constexpr (N == 4) asm volatile("s_waitcnt vmcnt(4)" ::: "memory");
  else if constexpr (N == 8) asm volatile("s_waitcnt vmcnt(8)" ::: "memory");
  else                       asm volatile("s_waitcnt vmcnt(9)" ::: "memory");
  __builtin_amdgcn_sched_barrier(0);   // rule #18: pin ops after the waitcnt
}

#define MFMA16(a, b, c) __builtin_amdgcn_mfma_f32_16x16x32_bf16((a), (b), (c), 0, 0, 0)

// ---------- prep: rows -> bf16 + sum of squares (x and keys) ----------
__global__ void prep_rows(const float* __restrict__ in,
                          unsigned short* __restrict__ ob,
                          float* __restrict__ sums) {
  const int lane = threadIdx.x & 63, wv = threadIdx.x >> 6;
  const int row = blockIdx.x * 4 + wv;
  const float* rp = in + ((size_t)row << 9);
  float4 a = *(const float4*)(rp + lane * 8);
  float4 b = *(const float4*)(rp + lane * 8 + 4);
  float s = a.x*a.x + a.y*a.y + a.z*a.z + a.w*a.w
          + b.x*b.x + b.y*b.y + b.z*b.z + b.w*b.w;
  ushort8 o;
  o[0]=f2bf(a.x); o[1]=f2bf(a.y); o[2]=f2bf(a.z); o[3]=f2bf(a.w);
  o[4]=f2bf(b.x); o[5]=f2bf(b.y); o[6]=f2bf(b.z); o[7]=f2bf(b.w);
  *(ushort8*)(ob + ((size_t)row << 9) + lane * 8) = o;
  #pragma unroll
  for (int m = 32; m; m >>= 1) s += __shfl_xor(s, m);
  if (lane == 0) sums[row] = s;
}

// ---------- prep: V (16384x128) -> Vt bf16 (128x16384), sigma-permuted ----------
// Within each 32-d block, stored position p = 8q+j holds source d =
//   4q + j (j<4) ;  16 + 4q + j-4 (j>=4)   [R9-verified]
__global__ void prep_vt(const float* __restrict__ V,
                        unsigned short* __restrict__ Vt) {
  __shared__ float t[64][129];
  const int d0 = blockIdx.x * 64;
  const int tid = threadIdx.x;
  #pragma unroll
  for (int j = 0; j < 32; ++j) {
    int idx = j * 256 + tid;
    t[idx >> 7][idx & 127] = V[((size_t)d0 << 7) + idx];
  }
  __syncthreads();
  #pragma unroll
  for (int j = 0; j < 32; ++j) {
    int idx = j * 256 + tid;
    int cc = idx >> 6, dd = idx & 63;
    int p = dd & 31, qq = p >> 3, jj = p & 7;
    int src = (dd & 32) + 4 * qq + ((jj < 4) ? jj : (12 + jj));
    Vt[((size_t)cc << 14) + d0 + dd] = f2bf(t[src][cc]);
  }
}

// ---------- fused: 256 threads (4 waves = 2dw x 2bw), 64d x 64b wave tiles ----------
// R13 base, ONE change: amdgpu_waves_per_eu(2) instead of launch_bounds(256,1).
// R13's (256,1) allocated 176 arch VGPR + ~96 AGPR = ~272 unified > 256 ->
// occupancy collapsed to 1 wave/SIMD (11%).  waves_per_eu(2) forces total <= 256
// (2 waves/EU guaranteed), spilling only the ~16-reg overage (vs R12's 60-reg
// spill at the 128 cap).  2 blocks/CU x 4 waves = 2 waves/SIMD TLP restored.
__global__ __launch_bounds__(256)
__attribute__((amdgpu_waves_per_eu(2)))
void varkeys_fused(const unsigned short* __restrict__ xb,
                   const unsigned short* __restrict__ kb,
                   const unsigned short* __restrict__ vt,
                   const float* __restrict__ sx,
                   const float* __restrict__ sk,
                   float* __restrict__ kvp) {
  __shared__ __attribute__((aligned(16))) char lds[81920];
  char* const Vbuf = lds + 65536;            // 16KB: one 64-d half x 128 c

  const int tid  = threadIdx.x;
  const int lane = tid & 63;
  const int wv   = tid >> 6;                 // 0..3
  const int dw   = wv >> 1;                  // d-half / c-half owner
  const int bw   = wv & 1;                   // b-half
  const int c    = lane & 15;
  const int h    = lane >> 4;
  const int sw   = (lane & 7) << 4;
  const int l3   = lane >> 3;

  const int bid    = blockIdx.x;
  const int dslice = bid & 15;               // stride-16 -> XCD-pinned keys slice
  const int btile  = bid >> 4;
  const int b0     = btile * BT;
  const int dbase  = dslice * DSLICE;

  float sxv[4];
  #pragma unroll
  for (int fj = 0; fj < 4; ++fj) sxv[fj] = sx[b0 + bw * 64 + fj * 16 + c];

  // staging constants (R9-verified): per call 32 rows x 128B, linear dest
  const int rowT = wv * 8 + l3;                        // 0..31
  const int ofs  = (((lane & 7) ^ l3) << 4);           // swizzled in-row offset

  const char* xbB = (const char*)xb;
  const char* kbB = (const char*)kb;
  const char* vtB = (const char*)vt;

  const f32x4 zero = {0.f, 0.f, 0.f, 0.f};
  f32x4 acc[4][4];
  #pragma unroll
  for (int j = 0; j < 4; ++j)
    #pragma unroll
    for (int n = 0; n < 4; ++n) acc[j][n] = zero;

  // stage one 64-k step: keys 128 rows (4 calls) + x 128 rows (4 calls)
  auto stageAB = [&](int ns) {
    const int dg2 = dbase + (ns >> 3) * DCH;
    const int kb2 = (ns & 7) << 7;
    char* A2 = lds + (ns & 1) * 16384;
    char* B2 = lds + 32768 + (ns & 1) * 16384;
    #pragma unroll
    for (int cl = 0; cl < 4; ++cl)
      gl_lds16(kbB + ((size_t)(dg2 + cl * 32 + rowT) << 10) + kb2 + ofs,
               A2 + cl * 4096 + wv * 1024);
    #pragma unroll
    for (int cl = 0; cl < 4; ++cl)
      gl_lds16(xbB + ((size_t)(b0 + cl * 32 + rowT) << 10) + kb2 + ofs,
               B2 + cl * 4096 + wv * 1024);
  };

  stageAB(0);   // prologue: (dc=0, kk=0) -> buf0

  f32x4 skq[4];

  for (int dc = 0; dc < 8; ++dc) {
    const int dg = dbase + dc * DCH;

    f32x4 S[4][4];
    #pragma unroll
    for (int i = 0; i < 4; ++i)
      #pragma unroll
      for (int fj = 0; fj < 4; ++fj) S[i][fj] = zero;

    #pragma unroll
    for (int kk = 0; kk < 8; ++kk) {
      __builtin_amdgcn_s_barrier();          // A: buf[kk&1^1] reads done everywhere
      if (kk == 7) {                         // sk for this dc (own d-half)
        #pragma unroll
        for (int i = 0; i < 4; ++i)
          skq[i] = *(const f32x4*)(sk + dg + dw * 64 + i * 16 + h * 4);
      }
      const int ns = dc * 8 + kk + 1;
      if (kk < 7) {
        stageAB(ns);                         // 8 calls
      } else if (dc < 7) {                   // As half of kk0-next into As[0]
        const int dg2 = dbase + (dc + 1) * DCH;
        #pragma unroll
        for (int cl = 0; cl < 4; ++cl)
          gl_lds16(kbB + ((size_t)(dg2 + cl * 32 + rowT) << 10) + ofs,
                   lds + cl * 4096 + wv * 1024);
      }
      if (kk >= 2 && kk <= 5)                // V half0: one 4KB call per kk
        gl_lds16(vtB + ((size_t)((kk - 2) * 32 + rowT) << 15)
                     + ((size_t)dg << 1) + ofs,
                 Vbuf + (kk - 2) * 4096 + wv * 1024);
      if (kk == 7)      { if (dc < 7) waitv<4>(); else waitv<0>(); }
      else if (kk >= 2 && kk <= 5) waitv<9>();
      else                         waitv<8>();
      __builtin_amdgcn_s_barrier();          // B: this kk's buffers landed
      __builtin_amdgcn_sched_barrier(0);

      // GEMM1 k-step on buf[kk&1]: 16 ds_reads, 32 MFMA per wave (64d x 64b)
      const char* As = lds + (kk & 1) * 16384;
      const char* Bs = lds + 32768 + (kk & 1) * 16384;
      __builtin_amdgcn_s_setprio(1);
      #pragma unroll
      for (int kf = 0; kf < 2; ++kf) {
        const int ko = (kf * 64 + h * 16) ^ sw;
        short8 bf[4];
        #pragma unroll
        for (int fj = 0; fj < 4; ++fj)
          bf[fj] = *(const short8*)(Bs + ((bw * 64 + fj * 16 + c) << 7) + ko);
        #pragma unroll
        for (int i = 0; i < 4; ++i) {
          short8 af = *(const short8*)(As + ((dw * 64 + i * 16 + c) << 7) + ko);
          #pragma unroll
          for (int fj = 0; fj < 4; ++fj)
            S[i][fj] = MFMA16(af, bf[fj], S[i][fj]);
        }
      }
      __builtin_amdgcn_s_setprio(0);
    }

    // ---- transform -> Ps (overlays Bs region; same-lane sigma words) ----
    __builtin_amdgcn_s_barrier();            // all GEMM1 Bs reads complete
    {
      char* const PsW = lds + 32768 + dw * 16384 + bw * 8192;
      #pragma unroll
      for (int dk = 0; dk < 2; ++dk) {
        #pragma unroll
        for (int fj = 0; fj < 4; ++fj) {
          const float sv = sxv[fj];
          const f32x4 sA = S[2 * dk][fj];
          const f32x4 sB = S[2 * dk + 1][fj];
          const f32x4 kA = skq[2 * dk];
          const f32x4 kB = skq[2 * dk + 1];
          float a0 = 10000.f * __builtin_amdgcn_rcpf(kA[0] + sv - 2.f * sA[0] + 1.f);
          float a1 = 10000.f * __builtin_amdgcn_rcpf(kA[1] + sv - 2.f * sA[1] + 1.f);
          float a2 = 10000.f * __builtin_amdgcn_rcpf(kA[2] + sv - 2.f * sA[2] + 1.f);
          float a3 = 10000.f * __builtin_amdgcn_rcpf(kA[3] + sv - 2.f * sA[3] + 1.f);
          float e0 = 10000.f * __builtin_amdgcn_rcpf(kB[0] + sv - 2.f * sB[0] + 1.f);
          float e1 = 10000.f * __builtin_amdgcn_rcpf(kB[1] + sv - 2.f * sB[1] + 1.f);
          float e2 = 10000.f * __builtin_amdgcn_rcpf(kB[2] + sv - 2.f * sB[2] + 1.f);
          float e3 = 10000.f * __builtin_amdgcn_rcpf(kB[3] + sv - 2.f * sB[3] + 1.f);
          intx4 fw;
          fw[0] = (int)cvtpk_bf16(a0, a1);
          fw[1] = (int)cvtpk_bf16(a2, a3);
          fw[2] = (int)cvtpk_bf16(e0, e1);
          fw[3] = (int)cvtpk_bf16(e2, e3);
          *(intx4*)(PsW + dk * 4096 + fj * 1024 + lane * 16) = fw;
        }
      }
    }
    asm volatile("s_waitcnt lgkmcnt(0)" ::: "memory");
    __builtin_amdgcn_sched_barrier(0);
    __builtin_amdgcn_s_barrier();            // Ps visible to partner waves

    // ---- GEMM2: two d-half phases; V restaged between with counted vmcnt ----
    #pragma unroll
    for (int ph = 0; ph < 2; ++ph) {
      const char* PsR = lds + 32768 + ph * 16384 + bw * 8192;
      __builtin_amdgcn_s_setprio(1);
      #pragma unroll
      for (int dk = 0; dk < 2; ++dk) {
        const int ko2 = (dk * 64 + h * 16) ^ sw;
        short8 pa[4], vb[4];
        #pragma unroll
        for (int fj = 0; fj < 4; ++fj)
          pa[fj] = *(const short8*)(PsR + dk * 4096 + fj * 1024 + lane * 16);
        #pragma unroll
        for (int fc = 0; fc < 4; ++fc)
          vb[fc] = *(const short8*)(Vbuf + ((dw * 64 + fc * 16 + c) << 7) + ko2);
        #pragma unroll
        for (int fj = 0; fj < 4; ++fj)
          #pragma unroll
          for (int fc = 0; fc < 4; ++fc)
            acc[fj][fc] = MFMA16(pa[fj], vb[fc], acc[fj][fc]);
      }
      __builtin_amdgcn_s_setprio(0);
      if (ph == 0) {
        __builtin_amdgcn_s_barrier();        // phase0 Vbuf + Ps[0] reads done
        #pragma unroll
        for (int vr = 0; vr < 4; ++vr)       // V half1 (d 64..127 of chunk)
          gl_lds16(vtB + ((size_t)(vr * 32 + rowT) << 15)
                       + ((size_t)(dg + 64) << 1) + ofs,
                   Vbuf + vr * 4096 + wv * 1024);
        if (dc < 7) {                        // Bs half of kk0-next into Bs[0]
          #pragma unroll
          for (int cl = 0; cl < 4; ++cl)
            gl_lds16(xbB + ((size_t)(b0 + cl * 32 + rowT) << 10) + ofs,
                     lds + 32768 + cl * 4096 + wv * 1024);
          waitv<4>();                        // V half1 done; Bs-kk0 in flight
        } else {
          waitv<0>();
        }
        __builtin_amdgcn_s_barrier();        // V half1 visible
      }
    }
  }

  // ---- epilogue: each (b,c) owned by exactly one wave; straight store ----
  float* op = kvp + (((size_t)(dslice * BATCH + b0 + bw * 64)) << 7) + dw * 64;
  #pragma unroll
  for (int fj = 0; fj < 4; ++fj)
    #pragma unroll
    for (int r = 0; r < 4; ++r) {
      const int brow = fj * 16 + h * 4 + r;
      #pragma unroll
      for (int fc = 0; fc < 4; ++fc)
        op[((size_t)brow << 7) + fc * 16 + c] = acc[fj][fc][r];
    }
}

// ---------- reduce ND slices + row-normalize ----------
__global__ void reduce_norm(const float* __restrict__ part, float* __restrict__ out) {
  const int lane = threadIdx.x & 63, wv = threadIdx.x >> 6;
  const int b = blockIdx.x * 4 + wv;
  float v0 = 0.f, v1 = 0.f;
  #pragma unroll
  for (int s = 0; s < ND; ++s) {
    const float* p = part + ((((size_t)s << 12) + b) << 7);
    v0 += p[lane]; v1 += p[lane + 64];
  }
  float t = v0 + v1;
  #pragma unroll
  for (int m = 32; m; m >>= 1) t += __shfl_xor(t, m);
  out[((size_t)b << 7) + lane]      = v0 / t;
  out[((size_t)b << 7) + lane + 64] = v1 / t;
}

extern "C" void kernel_launch(void* const* d_in, const int* in_sizes, int n_in,
                              void* d_out, int out_size, void* d_ws, size_t ws_size,
                              hipStream_t stream) {
  (void)in_sizes; (void)n_in; (void)out_size; (void)ws_size;
  const float* x    = (const float*)d_in[0];
  const float* keys = (const float*)d_in[1];
  const float* V    = (const float*)d_in[2];
  float* out = (float*)d_out;
  char* ws = (char*)d_ws;
  // ws (57MB): xb 4M | kb 16M @4M | vt 4M @20M | sx @24M | sk @24M+64K | kvp 32M @25M
  unsigned short* xb = (unsigned short*)(ws);
  unsigned short* kb = (unsigned short*)(ws + ((size_t)4 << 20));
  unsigned short* vt = (unsigned short*)(ws + ((size_t)20 << 20));
  float* sx  = (float*)(ws + ((size_t)24 << 20));
  float* sk  = (float*)(ws + ((size_t)24 << 20) + (1 << 16));
  float* kvp = (float*)(ws + ((size_t)25 << 20));

  prep_rows<<<BATCH / 4, 256, 0, stream>>>(x, xb, sx);
  prep_rows<<<DICT / 4, 256, 0, stream>>>(keys, kb, sk);
  prep_vt<<<DICT / 64, 256, 0, stream>>>(V, vt);
  varkeys_fused<<<(BATCH / BT) * ND, 256, 0, stream>>>(xb, kb, vt, sx, sk, kvp);
  reduce_norm<<<BATCH / 4, 256, 0, stream>>>(kvp, out);
}

// Round 16
// 130.206 us; speedup vs baseline: 1.2025x; 1.2025x over previous
//
#include <hip/hip_runtime.h>

#define BATCH 4096
#define DICT  16384
#define KDIM  512
#define CAT   128
#define ND    16              // split-K over dict
#define DSLICE (DICT/ND)      // 1024
#define DCH   64              // d-chunk per dc iteration
#define BT    256             // b rows per block (8 waves x 32)

typedef __attribute__((ext_vector_type(4))) float          f32x4;
typedef __attribute__((ext_vector_type(8))) short          short8;
typedef __attribute__((ext_vector_type(8))) unsigned short ushort8;
typedef __attribute__((ext_vector_type(4))) int            intx4;

__device__ __forceinline__ unsigned short f2bf(float f) {
  unsigned int u = __float_as_uint(f);
  return (unsigned short)((u + 0x7fffu + ((u >> 16) & 1u)) >> 16);  // RNE
}

__device__ __forceinline__ unsigned int cvtpk_bf16(float lo, float hi) {
  unsigned int r;
  asm volatile("v_cvt_pk_bf16_f32 %0, %1, %2" : "=v"(r) : "v"(lo), "v"(hi));
  return r;
}

#define AS1 __attribute__((address_space(1)))
#define AS3 __attribute__((address_space(3)))
__device__ __forceinline__ void gl_lds16(const void* g, void* l) {
  // 16B/lane; LDS dest = wave-uniform base + lane*16 (linear). Swizzle is
  // pre-applied on the GLOBAL source address (m173 pattern).
  __builtin_amdgcn_global_load_lds((AS1 void*)(g), (AS3 void*)(l), 16, 0, 0);
}

template <int N>
__device__ __forceinline__ void waitv() {
  if constexpr (N == 0)      asm volatile("s_waitcnt vmcnt(0)" ::: "memory");
  else if constexpr (N == 5) asm volatile("s_waitcnt vmcnt(5)" ::: "memory");
  else                       asm volatile("s_waitcnt vmcnt(6)" ::: "memory");
  __builtin_amdgcn_sched_barrier(0);   // rule #18: pin ops after the waitcnt
}

#define MFMA16(a, b, c) __builtin_amdgcn_mfma_f32_16x16x32_bf16((a), (b), (c), 0, 0, 0)

// ---------- merged prep: x rows | keys rows | sigma-permuted Vt, one launch ----------
// blocks 0..1023: x -> xb + sx ; 1024..5119: keys -> kb + sk ; 5120..5375: V -> Vt.
// Branch is block-uniform (blockIdx), so the vt-branch __syncthreads is safe.
__global__ void prep_all(const float* __restrict__ x,
                         const float* __restrict__ keys,
                         const float* __restrict__ V,
                         unsigned short* __restrict__ xb,
                         unsigned short* __restrict__ kb,
                         unsigned short* __restrict__ vt,
                         float* __restrict__ sx,
                         float* __restrict__ sk) {
  __shared__ float t[64][129];
  const int b = blockIdx.x;
  const int tid = threadIdx.x;
  if (b < 5120) {
    // ---- prep_rows (R9-verified body) ----
    const float* in = (b < 1024) ? x : keys;
    unsigned short* ob = (b < 1024) ? xb : kb;
    float* sums = (b < 1024) ? sx : sk;
    const int rb = (b < 1024) ? b : (b - 1024);
    const int lane = tid & 63, wv = tid >> 6;
    const int row = rb * 4 + wv;
    const float* rp = in + ((size_t)row << 9);
    float4 a = *(const float4*)(rp + lane * 8);
    float4 bb = *(const float4*)(rp + lane * 8 + 4);
    float s = a.x*a.x + a.y*a.y + a.z*a.z + a.w*a.w
            + bb.x*bb.x + bb.y*bb.y + bb.z*bb.z + bb.w*bb.w;
    ushort8 o;
    o[0]=f2bf(a.x); o[1]=f2bf(a.y); o[2]=f2bf(a.z); o[3]=f2bf(a.w);
    o[4]=f2bf(bb.x); o[5]=f2bf(bb.y); o[6]=f2bf(bb.z); o[7]=f2bf(bb.w);
    *(ushort8*)(ob + ((size_t)row << 9) + lane * 8) = o;
    #pragma unroll
    for (int m = 32; m; m >>= 1) s += __shfl_xor(s, m);
    if (lane == 0) sums[row] = s;
  } else {
    // ---- prep_vt, sigma-permuted (R9-verified body) ----
    // Within each 32-d block, stored position p = 8q+j holds source d =
    //   4q + j (j<4) ;  16 + 4q + j-4 (j>=4)
    const int d0 = (b - 5120) * 64;
    #pragma unroll
    for (int j = 0; j < 32; ++j) {
      int idx = j * 256 + tid;
      t[idx >> 7][idx & 127] = V[((size_t)d0 << 7) + idx];
    }
    __syncthreads();
    #pragma unroll
    for (int j = 0; j < 32; ++j) {
      int idx = j * 256 + tid;
      int cc = idx >> 6, dd = idx & 63;
      int p = dd & 31, qq = p >> 3, jj = p & 7;
      int src = (dd & 32) + 4 * qq + ((jj < 4) ? jj : (12 + jj));
      vt[((size_t)cc << 14) + d0 + dd] = f2bf(t[src][cc]);
    }
  }
}

// ---------- fused kernel: R9 (session-best, 113.2us verified), byte-identical ----------
// 512 threads (8 waves), BT=256, 1 block/CU.  LDS 128KB:
//   As dbuf 2x8KB | Bs dbuf 2x32KB | Vs 16KB | (rest idle until epilogue bounce)
// Per k-step: s_barrier ; stage(next) ; s_waitcnt vmcnt(C>0) ; s_barrier ; MFMA(cur).
// P never touches LDS: kern->bf16 via v_cvt_pk_bf16_f32 straight from S regs
// (sigma-permuted Vt makes the k-slot assignment lane-local).
__global__ __launch_bounds__(512, 2)
void varkeys_fused(const unsigned short* __restrict__ xb,
                   const unsigned short* __restrict__ kb,
                   const unsigned short* __restrict__ vt,
                   const float* __restrict__ sx,
                   const float* __restrict__ sk,
                   float* __restrict__ kvp) {
  __shared__ __attribute__((aligned(16))) char lds[131072];
  char* const VsB = lds + 81920;             // 16KB

  const int tid  = threadIdx.x;
  const int lane = tid & 63;
  const int wv   = tid >> 6;                 // 0..7
  const int c    = lane & 15;
  const int h    = lane >> 4;                // = q
  const int sw   = (lane & 7) << 4;
  const int l3   = lane >> 3;

  const int bid    = blockIdx.x;
  const int btile  = bid & 15;
  const int dslice = bid >> 4;
  const int b0     = btile * BT;
  const int dbase  = dslice * DSLICE;

  const float sxv0 = sx[b0 + wv * 32 + c];
  const float sxv1 = sx[b0 + wv * 32 + 16 + c];

  // staging per-thread constants (linear LDS dest <-> swizzled global src)
  const int rowA  = wv * 8 + l3;                       // As row 0..63
  const int rowB0 = wv * 32 + l3;                      // Bs row base (+ r*8)
  const int ofs   = (((lane & 7) ^ l3) << 4);          // swizzled in-row offset

  const char* xbB = (const char*)xb;
  const char* kbB = (const char*)kb;
  const char* vtB = (const char*)vt;

  const f32x4 zero = {0.f, 0.f, 0.f, 0.f};
  f32x4 acc[2][8];
  #pragma unroll
  for (int i = 0; i < 2; ++i)
    #pragma unroll
    for (int j = 0; j < 8; ++j) acc[i][j] = zero;

  // prologue: stage (dc=0, kk=0) -> buf0   (5 loads/wave)
  gl_lds16(kbB + ((size_t)(dbase + rowA) << 10) + ofs, lds + wv * 1024);
  #pragma unroll
  for (int r = 0; r < 4; ++r)
    gl_lds16(xbB + ((size_t)(b0 + rowB0 + r * 8) << 10) + ofs,
             lds + 16384 + (wv * 4 + r) * 1024);

  f32x4 skq[4];

  for (int dc = 0; dc < DSLICE / DCH; ++dc) {
    const int dg = dbase + dc * DCH;

    f32x4 S[4][2];
    #pragma unroll
    for (int i = 0; i < 4; ++i) { S[i][0] = zero; S[i][1] = zero; }

    #pragma unroll
    for (int kk = 0; kk < 8; ++kk) {
      __builtin_amdgcn_s_barrier();          // A: all waves done reading buf[kk&1^1]
      if (kk == 0) {                         // sk for THIS dc (drained by waitv)
        #pragma unroll
        for (int i = 0; i < 4; ++i)
          skq[i] = *(const f32x4*)(sk + dg + i * 16 + h * 4);
      }
      // stage(ns+1) -> buf[(kk+1)&1]
      if (!(kk == 7 && dc == (DSLICE / DCH - 1))) {
        const int dg2 = (kk == 7) ? dg + DCH : dg;
        const int kb2 = ((kk + 1) & 7) << 7;
        char* A2 = lds + ((kk + 1) & 1) * 8192;
        char* B2 = lds + 16384 + ((kk + 1) & 1) * 32768;
        gl_lds16(kbB + ((size_t)(dg2 + rowA) << 10) + kb2 + ofs, A2 + wv * 1024);
        #pragma unroll
        for (int r = 0; r < 4; ++r)
          gl_lds16(xbB + ((size_t)(b0 + rowB0 + r * 8) << 10) + kb2 + ofs,
                   B2 + (wv * 4 + r) * 1024);
        if (kk == 3)   // V rows 0..63 of this dc (ready long before GEMM2)
          gl_lds16(vtB + ((size_t)(wv * 8 + l3) << 15) + ((size_t)dg << 1) + ofs,
                   VsB + wv * 1024);
        if (kk == 4)   // V rows 64..127
          gl_lds16(vtB + ((size_t)(64 + wv * 8 + l3) << 15) + ((size_t)dg << 1) + ofs,
                   VsB + 8192 + wv * 1024);
      }
      // wait: exactly this step's issues remain in flight -> prev step's landed
      if (kk == 7) { if (dc == DSLICE / DCH - 1) waitv<0>(); else waitv<5>(); }
      else if (kk == 3 || kk == 4) waitv<6>();
      else waitv<5>();
      __builtin_amdgcn_s_barrier();          // B: everyone's stage(ns) landed
      __builtin_amdgcn_sched_barrier(0);

      // GEMM1 k-step on buf[kk&1]  (R1/R5-verified fragment math)
      const char* As = lds + (kk & 1) * 8192;
      const char* Bs = lds + 16384 + (kk & 1) * 32768;
      #pragma unroll
      for (int kf = 0; kf < 2; ++kf) {
        const int ko = (kf * 64 + h * 16) ^ sw;
        short8 bf0 = *(const short8*)(Bs + ((wv * 32 + c) << 7) + ko);
        short8 bf1 = *(const short8*)(Bs + ((wv * 32 + 16 + c) << 7) + ko);
        #pragma unroll
        for (int i = 0; i < 4; ++i) {
          short8 af = *(const short8*)(As + ((i * 16 + c) << 7) + ko);
          S[i][0] = MFMA16(af, bf0, S[i][0]);
          S[i][1] = MFMA16(af, bf1, S[i][1]);
        }
      }
    }

    // transform + in-register P (sigma layout) + GEMM2, per 32-d chunk dk
    // pa[fj] element j at lane (q=h, c):  j<4 -> kern(S[2dk][fj][j])    (d=32dk+4q+j)
    //                                     j>=4 -> kern(S[2dk+1][fj][j-4])
    // matches sigma-permuted Vt staged in VsB (prep_all).
    #pragma unroll
    for (int dk = 0; dk < 2; ++dk) {
      short8 pa[2];
      #pragma unroll
      for (int fj = 0; fj < 2; ++fj) {
        const float sxv = fj ? sxv1 : sxv0;
        const f32x4 sA = S[2 * dk][fj];
        const f32x4 sB = S[2 * dk + 1][fj];
        const f32x4 kA = skq[2 * dk];
        const f32x4 kB = skq[2 * dk + 1];
        float a0 = 10000.f * __builtin_amdgcn_rcpf(kA[0] + sxv - 2.f * sA[0] + 1.f);
        float a1 = 10000.f * __builtin_amdgcn_rcpf(kA[1] + sxv - 2.f * sA[1] + 1.f);
        float a2 = 10000.f * __builtin_amdgcn_rcpf(kA[2] + sxv - 2.f * sA[2] + 1.f);
        float a3 = 10000.f * __builtin_amdgcn_rcpf(kA[3] + sxv - 2.f * sA[3] + 1.f);
        float b0f = 10000.f * __builtin_amdgcn_rcpf(kB[0] + sxv - 2.f * sB[0] + 1.f);
        float b1f = 10000.f * __builtin_amdgcn_rcpf(kB[1] + sxv - 2.f * sB[1] + 1.f);
        float b2f = 10000.f * __builtin_amdgcn_rcpf(kB[2] + sxv - 2.f * sB[2] + 1.f);
        float b3f = 10000.f * __builtin_amdgcn_rcpf(kB[3] + sxv - 2.f * sB[3] + 1.f);
        intx4 fw;
        fw[0] = (int)cvtpk_bf16(a0, a1);
        fw[1] = (int)cvtpk_bf16(a2, a3);
        fw[2] = (int)cvtpk_bf16(b0f, b1f);
        fw[3] = (int)cvtpk_bf16(b2f, b3f);
        pa[fj] = *(short8*)&fw;
      }
      const int ko = (dk * 64 + h * 16) ^ sw;
      #pragma unroll
      for (int fc = 0; fc < 8; ++fc) {
        short8 vb = *(const short8*)(VsB + ((fc * 16 + c) << 7) + ko);
        acc[0][fc] = MFMA16(pa[0], vb, acc[0][fc]);
        acc[1][fc] = MFMA16(pa[1], vb, acc[1][fc]);
      }
    }
  }

  // epilogue: bounce acc through per-wave LDS, store full 128B lines
  __syncthreads();   // all main-loop LDS reads done; reuse whole LDS
  float* eb = (float*)(lds + (wv << 14));   // 16KB per wave
  #pragma unroll
  for (int fb = 0; fb < 2; ++fb)
    #pragma unroll
    for (int r = 0; r < 4; ++r) {
      const int brow = fb * 16 + h * 4 + r;
      #pragma unroll
      for (int fc = 0; fc < 8; ++fc)
        eb[(brow << 7) + fc * 16 + c] = acc[fb][fc][r];
    }
  // same-wave read-back (compiler inserts lgkmcnt), coalesced f32x4 stores
  float* op = kvp + (((size_t)dslice * BATCH + b0 + wv * 32) << 7);
  #pragma unroll
  for (int t = 0; t < 16; ++t) {
    const int row = t * 2 + (lane >> 5);
    f32x4 v = *(const f32x4*)(eb + (row << 7) + ((lane & 31) << 2));
    *(f32x4*)(op + (((size_t)row) << 7) + ((lane & 31) << 2)) = v;
  }
}

// ---------- reduce ND slices + row-normalize ----------
__global__ void reduce_norm(const float* __restrict__ part, float* __restrict__ out) {
  const int lane = threadIdx.x & 63, wv = threadIdx.x >> 6;
  const int b = blockIdx.x * 4 + wv;
  float v0 = 0.f, v1 = 0.f;
  #pragma unroll
  for (int s = 0; s < ND; ++s) {
    const float* p = part + ((((size_t)s << 12) + b) << 7);
    v0 += p[lane]; v1 += p[lane + 64];
  }
  float t = v0 + v1;
  #pragma unroll
  for (int m = 32; m; m >>= 1) t += __shfl_xor(t, m);
  out[((size_t)b << 7) + lane]      = v0 / t;
  out[((size_t)b << 7) + lane + 64] = v1 / t;
}

extern "C" void kernel_launch(void* const* d_in, const int* in_sizes, int n_in,
                              void* d_out, int out_size, void* d_ws, size_t ws_size,
                              hipStream_t stream) {
  (void)in_sizes; (void)n_in; (void)out_size; (void)ws_size;
  const float* x    = (const float*)d_in[0];
  const float* keys = (const float*)d_in[1];
  const float* V    = (const float*)d_in[2];
  float* out = (float*)d_out;
  char* ws = (char*)d_ws;
  // ws (57MB): xb 4M | kb 16M @4M | vt 4M @20M | sx @24M | sk @24M+64K | kvp 32M @25M
  unsigned short* xb = (unsigned short*)(ws);
  unsigned short* kb = (unsigned short*)(ws + ((size_t)4 << 20));
  unsigned short* vt = (unsigned short*)(ws + ((size_t)20 << 20));
  float* sx  = (float*)(ws + ((size_t)24 << 20));
  float* sk  = (float*)(ws + ((size_t)24 << 20) + (1 << 16));
  float* kvp = (float*)(ws + ((size_t)25 << 20));

  prep_all<<<BATCH / 4 + DICT / 4 + DICT / 64, 256, 0, stream>>>(
      x, keys, V, xb, kb, vt, sx, sk);
  varkeys_fused<<<(BATCH / BT) * ND, 512, 0, stream>>>(xb, kb, vt, sx, sk, kvp);
  reduce_norm<<<BATCH / 4, 256, 0, stream>>>(kvp, out);
}